// Round 1
// baseline (239.190 us; speedup 1.0000x reference)
//
#include <hip/hip_runtime.h>
#include <cstdint>

// Problem constants (from setup_inputs):
#define NPOINT   65536
#define NB       4
#define PPS      128
#define PTOT     (NB * PPS)        // 512
#define NC       32
#define WORDS    (NPOINT / 32)     // 2048 uint32 words per bitmask row

// d_ws layout (bytes):
//   [0, 4194304)            propMask  uint32[PTOT][WORDS]
//   [4194304, 4227072)      refMask   uint32[NB][WORDS]
//   [4227072, 4229120)      iou       float[PTOT]
#define WS_PROP_OFF  0
#define WS_REF_OFF   (PTOT * WORDS * 4)            // 4194304
#define WS_IOU_OFF   (WS_REF_OFF + NB * WORDS * 4) // 4227072
#define WS_ZERO_BYTES WS_IOU_OFF                   // zero prop+ref masks

// out layout (float32):
#define OUT_CLUS   0        // 16384
#define OUT_SELF   16384    // 128
#define OUT_SELI   16512    // 4
#define OUT_OFFS   16516    // 5
#define OUT_MASK   16521    // 4

// ---- Kernel 1: scatter pairs into per-proposal bitmasks --------------------
// pairs are [M,2] int32 (pid, global_point_id); two pairs per thread via int4.
__global__ void k_scatter(const int4* __restrict__ pairs2, int npairs2,
                          const int2* __restrict__ pairs_tail, int has_tail,
                          uint32_t* __restrict__ propMask) {
    int i = blockIdx.x * blockDim.x + threadIdx.x;
    if (i < npairs2) {
        int4 pr = pairs2[i];
        int n0 = pr.y & (NPOINT - 1);
        int n1 = pr.w & (NPOINT - 1);
        atomicOr(&propMask[(unsigned)pr.x * WORDS + (n0 >> 5)], 1u << (n0 & 31));
        atomicOr(&propMask[(unsigned)pr.z * WORDS + (n1 >> 5)], 1u << (n1 & 31));
    }
    if (i == 0 && has_tail) {
        int2 pr = pairs_tail[0];
        int n = pr.y & (NPOINT - 1);
        atomicOr(&propMask[(unsigned)pr.x * WORDS + (n >> 5)], 1u << (n & 31));
    }
}

// ---- Kernel 2: build reference-cluster bitmask per scene -------------------
__global__ void k_refmask(const int* __restrict__ labels,
                          const int* __restrict__ object_id,
                          uint32_t* __restrict__ refMask) {
    int i = blockIdx.x * blockDim.x + threadIdx.x;   // 0 .. NB*NPOINT-1
    int b = i >> 16;                                  // NPOINT == 65536
    bool match = (labels[i] == object_id[b]);
    unsigned long long bal = __ballot(match);         // 64-bit on wave64
    if ((threadIdx.x & 63) == 0) {
        int w = (i & (NPOINT - 1)) >> 5;              // word index of lane 0
        refMask[b * WORDS + w]     = (uint32_t)bal;
        refMask[b * WORDS + w + 1] = (uint32_t)(bal >> 32);
    }
}

// ---- Kernel 3: per-proposal IoU (one wave per proposal) --------------------
__global__ void k_iou(const uint32_t* __restrict__ propMask,
                      const uint32_t* __restrict__ refMask,
                      float* __restrict__ iou) {
    int p = blockIdx.x;
    int b = p >> 7;                                   // PPS == 128
    const uint4* pm = (const uint4*)(propMask + (size_t)p * WORDS);
    const uint4* rm = (const uint4*)(refMask + (size_t)b * WORDS);
    int lane = threadIdx.x;                           // blockDim == 64
    int inter = 0, cnt = 0, rsum = 0;
#pragma unroll
    for (int it = 0; it < (WORDS / 4) / 64; ++it) {   // 8 iterations
        uint4 a = pm[lane + it * 64];
        uint4 r = rm[lane + it * 64];
        inter += __popc(a.x & r.x) + __popc(a.y & r.y)
               + __popc(a.z & r.z) + __popc(a.w & r.w);
        cnt   += __popc(a.x) + __popc(a.y) + __popc(a.z) + __popc(a.w);
        rsum  += __popc(r.x) + __popc(r.y) + __popc(r.z) + __popc(r.w);
    }
#pragma unroll
    for (int off = 32; off; off >>= 1) {
        inter += __shfl_down(inter, off);
        cnt   += __shfl_down(cnt,   off);
        rsum  += __shfl_down(rsum,  off);
    }
    if (lane == 0) {
        float uni = (float)(cnt + rsum - inter);
        iou[p] = (uni > 0.0f) ? ((float)inter / fmaxf(uni, 1.0f)) : 0.0f;
    }
}

// ---- Kernel 4: copy feats -> clus_feats_batch ------------------------------
// slot = p - 128*b in [0,128) < MAXP always; each (b,slot) hit exactly once,
// so clus_feats_batch is a straight copy of feats (16384 floats).
__global__ void k_copyfeats(const float4* __restrict__ feats4,
                            float4* __restrict__ out4) {
    int i = blockIdx.x * blockDim.x + threadIdx.x;    // 0 .. 4095
    out4[i] = feats4[i];
}

// ---- Kernel 5: per-scene argmax + small outputs ----------------------------
__global__ void k_select(const float* __restrict__ iou,
                         const float* __restrict__ feats,
                         const int* __restrict__ pes,   // proposal_each_scene
                         float* __restrict__ out) {
    __shared__ float s_val[2];
    __shared__ int   s_idx[2];
    __shared__ int   s_best;
    int b = blockIdx.x;
    int t = threadIdx.x;                              // 0 .. 127
    int p = b * PPS + t;
    float v = iou[p];
    int idx = p;
    // wave argmax, first-index tie-break (matches jnp.argmax)
#pragma unroll
    for (int off = 32; off; off >>= 1) {
        float ov = __shfl_down(v,   off);
        int   oi = __shfl_down(idx, off);
        if (ov > v || (ov == v && oi < idx)) { v = ov; idx = oi; }
    }
    if ((t & 63) == 0) { s_val[t >> 6] = v; s_idx[t >> 6] = idx; }
    __syncthreads();
    if (t == 0) {
        float v0 = s_val[0], v1 = s_val[1];
        int   i0 = s_idx[0], i1 = s_idx[1];
        if (v1 > v0 || (v1 == v0 && i1 < i0)) { v0 = v1; i0 = i1; }
        bool has = pes[b] > 0;
        s_best = has ? i0 : -1;
        out[OUT_SELI + b] = has ? (float)i0 : -1.0f;
        out[OUT_MASK + b] = (v0 > 0.2f && has) ? 1.0f : 0.0f;
    }
    __syncthreads();
    int best = s_best;
    if (t < NC)
        out[OUT_SELF + b * NC + t] = (best >= 0) ? feats[best * NC + t] : 0.0f;
    if (b == 0 && t <= NB) {  // offsets = [0, cumsum(proposal_each_scene)]
        int s = 0;
        for (int i = 0; i < t; ++i) s += pes[i];
        out[OUT_OFFS + t] = (float)s;
    }
}

extern "C" void kernel_launch(void* const* d_in, const int* in_sizes, int n_in,
                              void* d_out, int out_size, void* d_ws, size_t ws_size,
                              hipStream_t stream) {
    const int*   proposals_idx = (const int*)d_in[0];
    const int*   pes           = (const int*)d_in[1];
    const int*   labels        = (const int*)d_in[2];
    const int*   object_id     = (const int*)d_in[3];
    const float* feats         = (const float*)d_in[4];

    const int M = in_sizes[0] / 2;                  // number of (pid, j) pairs
    uint32_t* propMask = (uint32_t*)((char*)d_ws + WS_PROP_OFF);
    uint32_t* refMask  = (uint32_t*)((char*)d_ws + WS_REF_OFF);
    float*    iou      = (float*)   ((char*)d_ws + WS_IOU_OFF);
    float*    out      = (float*)d_out;

    // zero the bitmask region (ws is poisoned 0xAA before every launch)
    hipMemsetAsync(d_ws, 0, WS_ZERO_BYTES, stream);

    int npairs2 = M / 2;
    int has_tail = M & 1;
    const int2* tail = ((const int2*)proposals_idx) + (M - 1);
    k_scatter<<<(npairs2 + 255) / 256, 256, 0, stream>>>(
        (const int4*)proposals_idx, npairs2, tail, has_tail, propMask);

    k_refmask<<<(NB * NPOINT) / 256, 256, 0, stream>>>(labels, object_id, refMask);

    k_iou<<<PTOT, 64, 0, stream>>>(propMask, refMask, iou);

    k_copyfeats<<<(PTOT * NC / 4) / 256, 256, 0, stream>>>(
        (const float4*)feats, (float4*)(out + OUT_CLUS));

    k_select<<<NB, PPS, 0, stream>>>(iou, feats, pes, out);
}

// Round 2
// 144.521 us; speedup vs baseline: 1.6551x; 1.6551x over previous
//
#include <hip/hip_runtime.h>
#include <cstdint>

// Problem constants (from setup_inputs):
#define NPOINT   65536
#define NB       4
#define PPS      128
#define PTOT     (NB * PPS)        // 512
#define NC       32
#define WORDS    (NPOINT / 32)     // 2048 uint32 words per bitmask row
#define NBLK     512               // blocks in the counting-sort passes
#define CAP      12288             // per-proposal bucket capacity (mean 7812, sigma ~88)

// ---------------- Path A ws layout (counting sort, no global atomics) -------
#define A_REF_OFF   0                              // refMask: 4*2048*4 = 32 KiB
#define A_IOU_OFF   32768                          // iou: 2 KiB
#define A_CNT_OFF   34816                          // binCount: 2 KiB
#define A_HIST_OFF  36864                          // hist[bin][NBLK]: 1 MiB
#define A_SORT_OFF  (36864 + PTOT * NBLK * 4)      // sortedN: PTOT*CAP*2 B
#define A_WS_NEED   ((size_t)A_SORT_OFF + (size_t)PTOT * CAP * 2)

// ---------------- Path B ws layout (round-1 fallback, global atomics) -------
#define B_PROP_OFF  0
#define B_REF_OFF   (PTOT * WORDS * 4)             // 4194304
#define B_IOU_OFF   (B_REF_OFF + NB * WORDS * 4)   // 4227072
#define B_ZERO_BYTES B_IOU_OFF

// out layout (float32):
#define OUT_CLUS   0        // 16384
#define OUT_SELF   16384    // 128
#define OUT_SELI   16512    // 4
#define OUT_OFFS   16516    // 5
#define OUT_MASK   16521    // 4

// ===================== shared kernels (both paths) ==========================

// reference-cluster bitmask per scene (ballot, no atomics)
__global__ void k_refmask(const int* __restrict__ labels,
                          const int* __restrict__ object_id,
                          uint32_t* __restrict__ refMask) {
    int i = blockIdx.x * blockDim.x + threadIdx.x;   // 0 .. NB*NPOINT-1
    int b = i >> 16;                                  // NPOINT == 65536
    bool match = (labels[i] == object_id[b]);
    unsigned long long bal = __ballot(match);         // 64-bit on wave64
    if ((threadIdx.x & 63) == 0) {
        int w = (i & (NPOINT - 1)) >> 5;
        refMask[b * WORDS + w]     = (uint32_t)bal;
        refMask[b * WORDS + w + 1] = (uint32_t)(bal >> 32);
    }
}

// feats -> clus_feats_batch is a straight copy (slot = p - 128*b, all < MAXP)
__global__ void k_copyfeats(const float4* __restrict__ feats4,
                            float4* __restrict__ out4) {
    int i = blockIdx.x * blockDim.x + threadIdx.x;    // 0 .. 4095
    out4[i] = feats4[i];
}

// per-scene argmax + small outputs
__global__ void k_select(const float* __restrict__ iou,
                         const float* __restrict__ feats,
                         const int* __restrict__ pes,
                         float* __restrict__ out) {
    __shared__ float s_val[2];
    __shared__ int   s_idx[2];
    __shared__ int   s_best;
    int b = blockIdx.x;
    int t = threadIdx.x;                              // 0 .. 127
    int p = b * PPS + t;
    float v = iou[p];
    int idx = p;
#pragma unroll
    for (int off = 32; off; off >>= 1) {
        float ov = __shfl_down(v,   off);
        int   oi = __shfl_down(idx, off);
        if (ov > v || (ov == v && oi < idx)) { v = ov; idx = oi; }
    }
    if ((t & 63) == 0) { s_val[t >> 6] = v; s_idx[t >> 6] = idx; }
    __syncthreads();
    if (t == 0) {
        float v0 = s_val[0], v1 = s_val[1];
        int   i0 = s_idx[0], i1 = s_idx[1];
        if (v1 > v0 || (v1 == v0 && i1 < i0)) { v0 = v1; i0 = i1; }
        bool has = pes[b] > 0;
        s_best = has ? i0 : -1;
        out[OUT_SELI + b] = has ? (float)i0 : -1.0f;
        out[OUT_MASK + b] = (v0 > 0.2f && has) ? 1.0f : 0.0f;
    }
    __syncthreads();
    int best = s_best;
    if (t < NC)
        out[OUT_SELF + b * NC + t] = (best >= 0) ? feats[best * NC + t] : 0.0f;
    if (b == 0 && t <= NB) {
        int s = 0;
        for (int i = 0; i < t; ++i) s += pes[i];
        out[OUT_OFFS + t] = (float)s;
    }
}

// ===================== Path A: counting sort + fused IoU ====================

// K1: per-block LDS histogram of proposal ids -> hist[bin][blk]
__global__ void k_hist(const int2* __restrict__ pairs, int M,
                       uint32_t* __restrict__ hist) {
    __shared__ uint32_t lh[PTOT];
    int blk = blockIdx.x, tid = threadIdx.x;
    for (int b = tid; b < PTOT; b += 256) lh[b] = 0;
    __syncthreads();
    int per = (M + NBLK - 1) / NBLK;
    int lo = blk * per;
    int hi = min(M, lo + per);
    for (int i = lo + tid; i < hi; i += 256)
        atomicAdd(&lh[pairs[i].x], 1u);
    __syncthreads();
    for (int b = tid; b < PTOT; b += 256)
        hist[b * NBLK + blk] = lh[b];
}

// K2: per-bin exclusive scan over NBLK=512 block counts; hist becomes absolute
// write bases (bin*CAP + prefix). One block (256 thr, 2 elems/thr) per bin.
__global__ void k_scan(uint32_t* __restrict__ hist,
                       uint32_t* __restrict__ binCount) {
    __shared__ uint32_t wsum[4];
    int bin = blockIdx.x, t = threadIdx.x;
    uint32_t* h = hist + bin * NBLK;
    uint32_t a = h[2 * t], b = h[2 * t + 1];
    uint32_t s = a + b;
    uint32_t inc = s;
#pragma unroll
    for (int off = 1; off < 64; off <<= 1) {
        uint32_t v = __shfl_up(inc, off);
        if ((t & 63) >= off) inc += v;
    }
    int w = t >> 6;
    if ((t & 63) == 63) wsum[w] = inc;
    __syncthreads();
    uint32_t wbase = 0;
    for (int i = 0; i < w; ++i) wbase += wsum[i];
    uint32_t excl = wbase + inc - s;
    uint32_t base = (uint32_t)bin * CAP + excl;
    h[2 * t]     = base;
    h[2 * t + 1] = base + a;
    if (t == 255) binCount[bin] = wbase + inc;   // total count for this bin
}

// K3: placement — LDS ranks, no global atomics; store point id as uint16
__global__ void k_place(const int2* __restrict__ pairs, int M,
                        const uint32_t* __restrict__ hist,
                        uint16_t* __restrict__ sortedN) {
    __shared__ uint32_t lbase[PTOT];
    __shared__ uint32_t lrank[PTOT];
    int blk = blockIdx.x, tid = threadIdx.x;
    for (int b = tid; b < PTOT; b += 256) {
        lbase[b] = hist[b * NBLK + blk];
        lrank[b] = 0;
    }
    __syncthreads();
    int per = (M + NBLK - 1) / NBLK;
    int lo = blk * per;
    int hi = min(M, lo + per);
    for (int i = lo + tid; i < hi; i += 256) {
        int2 pr = pairs[i];
        uint32_t r = atomicAdd(&lrank[pr.x], 1u);       // LDS atomic
        uint32_t pos = lbase[pr.x] + r;
        if (pos < (uint32_t)(pr.x + 1) * CAP)           // capacity guard
            sortedN[pos] = (uint16_t)(pr.y & (NPOINT - 1));
    }
}

// K4: build proposal bitmask in LDS, popcount vs refMask, write IoU
__global__ void k_iou_fused(const uint16_t* __restrict__ sortedN,
                            const uint32_t* __restrict__ binCount,
                            const uint32_t* __restrict__ refMask,
                            float* __restrict__ iou) {
    __shared__ uint32_t bm[WORDS];                      // 8 KiB
    __shared__ int red[12];
    int p = blockIdx.x, tid = threadIdx.x;              // 256 threads
    int b = p >> 7;
    for (int w = tid; w < WORDS; w += 256) bm[w] = 0;
    __syncthreads();
    uint32_t cnt0 = binCount[p];
    if (cnt0 > CAP) cnt0 = CAP;
    const uint16_t* lst = sortedN + (size_t)p * CAP;
    for (uint32_t i = tid; i < cnt0; i += 256) {
        uint32_t n = lst[i];
        atomicOr(&bm[n >> 5], 1u << (n & 31));          // LDS atomic
    }
    __syncthreads();
    int inter = 0, cnt = 0, rsum = 0;
    const uint32_t* rm = refMask + b * WORDS;
    for (int w = tid; w < WORDS; w += 256) {            // stride-256 words: 2-way LDS alias (free)
        uint32_t a = bm[w], r = rm[w];
        inter += __popc(a & r);
        cnt   += __popc(a);
        rsum  += __popc(r);
    }
#pragma unroll
    for (int off = 32; off; off >>= 1) {
        inter += __shfl_down(inter, off);
        cnt   += __shfl_down(cnt,   off);
        rsum  += __shfl_down(rsum,  off);
    }
    int w = tid >> 6;
    if ((tid & 63) == 0) { red[w] = inter; red[4 + w] = cnt; red[8 + w] = rsum; }
    __syncthreads();
    if (tid == 0) {
        inter = red[0] + red[1] + red[2] + red[3];
        cnt   = red[4] + red[5] + red[6] + red[7];
        rsum  = red[8] + red[9] + red[10] + red[11];
        float uni = (float)(cnt + rsum - inter);
        iou[p] = (uni > 0.0f) ? ((float)inter / fmaxf(uni, 1.0f)) : 0.0f;
    }
}

// ===================== Path B: round-1 fallback (global atomics) ============

__global__ void k_scatterB(const int4* __restrict__ pairs2, int npairs2,
                           const int2* __restrict__ pairs_tail, int has_tail,
                           uint32_t* __restrict__ propMask) {
    int i = blockIdx.x * blockDim.x + threadIdx.x;
    if (i < npairs2) {
        int4 pr = pairs2[i];
        int n0 = pr.y & (NPOINT - 1);
        int n1 = pr.w & (NPOINT - 1);
        atomicOr(&propMask[(unsigned)pr.x * WORDS + (n0 >> 5)], 1u << (n0 & 31));
        atomicOr(&propMask[(unsigned)pr.z * WORDS + (n1 >> 5)], 1u << (n1 & 31));
    }
    if (i == 0 && has_tail) {
        int2 pr = pairs_tail[0];
        int n = pr.y & (NPOINT - 1);
        atomicOr(&propMask[(unsigned)pr.x * WORDS + (n >> 5)], 1u << (n & 31));
    }
}

__global__ void k_iouB(const uint32_t* __restrict__ propMask,
                       const uint32_t* __restrict__ refMask,
                       float* __restrict__ iou) {
    int p = blockIdx.x;
    int b = p >> 7;
    const uint4* pm = (const uint4*)(propMask + (size_t)p * WORDS);
    const uint4* rm = (const uint4*)(refMask + (size_t)b * WORDS);
    int lane = threadIdx.x;
    int inter = 0, cnt = 0, rsum = 0;
#pragma unroll
    for (int it = 0; it < (WORDS / 4) / 64; ++it) {
        uint4 a = pm[lane + it * 64];
        uint4 r = rm[lane + it * 64];
        inter += __popc(a.x & r.x) + __popc(a.y & r.y)
               + __popc(a.z & r.z) + __popc(a.w & r.w);
        cnt   += __popc(a.x) + __popc(a.y) + __popc(a.z) + __popc(a.w);
        rsum  += __popc(r.x) + __popc(r.y) + __popc(r.z) + __popc(r.w);
    }
#pragma unroll
    for (int off = 32; off; off >>= 1) {
        inter += __shfl_down(inter, off);
        cnt   += __shfl_down(cnt,   off);
        rsum  += __shfl_down(rsum,  off);
    }
    if (lane == 0) {
        float uni = (float)(cnt + rsum - inter);
        iou[p] = (uni > 0.0f) ? ((float)inter / fmaxf(uni, 1.0f)) : 0.0f;
    }
}

// ===========================================================================

extern "C" void kernel_launch(void* const* d_in, const int* in_sizes, int n_in,
                              void* d_out, int out_size, void* d_ws, size_t ws_size,
                              hipStream_t stream) {
    const int*   proposals_idx = (const int*)d_in[0];
    const int*   pes           = (const int*)d_in[1];
    const int*   labels        = (const int*)d_in[2];
    const int*   object_id     = (const int*)d_in[3];
    const float* feats         = (const float*)d_in[4];

    const int M = in_sizes[0] / 2;
    float* out = (float*)d_out;

    k_copyfeats<<<(PTOT * NC / 4) / 256, 256, 0, stream>>>(
        (const float4*)feats, (float4*)(out + OUT_CLUS));

    if (ws_size >= A_WS_NEED) {
        // -------- Path A: no global atomics --------
        uint32_t* refMask  = (uint32_t*)((char*)d_ws + A_REF_OFF);
        float*    iou      = (float*)   ((char*)d_ws + A_IOU_OFF);
        uint32_t* binCount = (uint32_t*)((char*)d_ws + A_CNT_OFF);
        uint32_t* hist     = (uint32_t*)((char*)d_ws + A_HIST_OFF);
        uint16_t* sortedN  = (uint16_t*)((char*)d_ws + A_SORT_OFF);

        k_refmask<<<(NB * NPOINT) / 256, 256, 0, stream>>>(labels, object_id, refMask);
        k_hist   <<<NBLK, 256, 0, stream>>>((const int2*)proposals_idx, M, hist);
        k_scan   <<<PTOT, 256, 0, stream>>>(hist, binCount);
        k_place  <<<NBLK, 256, 0, stream>>>((const int2*)proposals_idx, M, hist, sortedN);
        k_iou_fused<<<PTOT, 256, 0, stream>>>(sortedN, binCount, refMask, iou);
        k_select <<<NB, PPS, 0, stream>>>(iou, feats, pes, out);
    } else {
        // -------- Path B: round-1 fallback --------
        uint32_t* propMask = (uint32_t*)((char*)d_ws + B_PROP_OFF);
        uint32_t* refMask  = (uint32_t*)((char*)d_ws + B_REF_OFF);
        float*    iou      = (float*)   ((char*)d_ws + B_IOU_OFF);

        hipMemsetAsync(d_ws, 0, B_ZERO_BYTES, stream);
        int npairs2 = M / 2;
        int has_tail = M & 1;
        const int2* tail = ((const int2*)proposals_idx) + (M - 1);
        k_scatterB<<<(npairs2 + 255) / 256, 256, 0, stream>>>(
            (const int4*)proposals_idx, npairs2, tail, has_tail, propMask);
        k_refmask<<<(NB * NPOINT) / 256, 256, 0, stream>>>(labels, object_id, refMask);
        k_iouB<<<PTOT, 64, 0, stream>>>(propMask, refMask, iou);
        k_select<<<NB, PPS, 0, stream>>>(iou, feats, pes, out);
    }
}

// Round 3
// 139.104 us; speedup vs baseline: 1.7195x; 1.0389x over previous
//
#include <hip/hip_runtime.h>
#include <cstdint>

// Problem constants (from setup_inputs):
#define NPOINT   65536
#define NB       4
#define PPS      128
#define PTOT     (NB * PPS)        // 512
#define NC       32
#define WORDS    (NPOINT / 32)     // 2048 uint32 words per bitmask row
#define NBLK     512               // build blocks (chunked over M)
#define CAP      12288             // per-proposal bucket capacity (mean 7812)

// ---------------- ws layout -------------------------------------------------
#define WS_REF_OFF   0                             // refMask: 4*2048*4 = 32 KiB
#define WS_IOU_OFF   32768                         // iou: 2 KiB
#define WS_CNT_OFF   34816                         // gcnt[PTOT]: 2 KiB
#define WS_SORT_OFF  36864                         // sortedN: PTOT*CAP*2 B
#define WS_NEED      ((size_t)WS_SORT_OFF + (size_t)PTOT * CAP * 2)

// out layout (float32):
#define OUT_CLUS   0        // 16384
#define OUT_SELF   16384    // 128
#define OUT_SELI   16512    // 4
#define OUT_OFFS   16516    // 5
#define OUT_MASK   16521    // 4

// ==== Kernel 1: fused build (counting-sort via atomic reserve) + refmask ====
// Blocks [0, NBLK): bucket the (pid, point) pairs into sortedN.
// Blocks [NBLK, NBLK+1024): refmask ballot; first 16 also copy feats->out.
__global__ void k_fused_build(const int2* __restrict__ pairs, int M,
                              const int* __restrict__ labels,
                              const int* __restrict__ object_id,
                              const float4* __restrict__ feats4,
                              float4* __restrict__ clus4,
                              uint32_t* __restrict__ gcnt,
                              uint32_t* __restrict__ refMask,
                              uint16_t* __restrict__ sortedN) {
    __shared__ uint32_t cnt[PTOT];   // pass1: per-bin count; pass2: rank
    __shared__ uint32_t base[PTOT];  // reserved base within bucket
    int bid = blockIdx.x, tid = threadIdx.x;

    if (bid >= NBLK) {
        // ---- refmask part (1024 blocks x 256 threads over NB*NPOINT) ----
        int rb = bid - NBLK;
        int i = rb * 256 + tid;                 // 0 .. 262143
        int b = i >> 16;
        bool match = (labels[i] == object_id[b]);
        unsigned long long bal = __ballot(match);
        if ((tid & 63) == 0) {
            int w = (i & (NPOINT - 1)) >> 5;
            refMask[b * WORDS + w]     = (uint32_t)bal;
            refMask[b * WORDS + w + 1] = (uint32_t)(bal >> 32);
        }
        // ---- feats -> clus_feats_batch (straight copy, 4096 float4) ----
        if (rb < 16) clus4[rb * 256 + tid] = feats4[rb * 256 + tid];
        return;
    }

    // ---- build part ----
    for (int b = tid; b < PTOT; b += 256) cnt[b] = 0;
    __syncthreads();

    int per = (M + NBLK - 1) / NBLK;
    int lo = bid * per;
    int hi = min(M, lo + per);

    // pass 1: histogram this chunk
    for (int i = lo + tid; i < hi; i += 256)
        atomicAdd(&cnt[pairs[i].x], 1u);
    __syncthreads();

    // reserve space in each bucket (<=512 global atomics per block,
    // distributed over 512 distinct words)
    for (int b = tid; b < PTOT; b += 256) {
        uint32_t c = cnt[b];
        base[b] = c ? atomicAdd(&gcnt[b], c) : 0u;
        cnt[b] = 0;                              // reuse as rank counter
    }
    __syncthreads();

    // pass 2: place (chunk is L2-hot from pass 1); order irrelevant
    for (int i = lo + tid; i < hi; i += 256) {
        int2 pr = pairs[i];
        uint32_t r = atomicAdd(&cnt[pr.x], 1u);  // LDS rank
        uint32_t pos = base[pr.x] + r;
        if (pos < CAP)
            sortedN[(size_t)pr.x * CAP + pos] = (uint16_t)(pr.y & (NPOINT - 1));
    }
}

// ==== Kernel 2: build proposal bitmask in LDS, popcount vs refMask ==========
__global__ void k_iou_fused(const uint16_t* __restrict__ sortedN,
                            const uint32_t* __restrict__ gcnt,
                            const uint32_t* __restrict__ refMask,
                            float* __restrict__ iou) {
    __shared__ uint32_t bm[WORDS];                      // 8 KiB
    __shared__ int red[12];
    int p = blockIdx.x, tid = threadIdx.x;              // 256 threads
    int b = p >> 7;
    for (int w = tid; w < WORDS; w += 256) bm[w] = 0;
    __syncthreads();
    uint32_t cnt0 = gcnt[p];
    if (cnt0 > CAP) cnt0 = CAP;
    const uint16_t* lst = sortedN + (size_t)p * CAP;
    for (uint32_t i = tid; i < cnt0; i += 256) {
        uint32_t n = lst[i];
        atomicOr(&bm[n >> 5], 1u << (n & 31));          // LDS atomic
    }
    __syncthreads();
    int inter = 0, cnt = 0, rsum = 0;
    const uint32_t* rm = refMask + b * WORDS;
    for (int w = tid; w < WORDS; w += 256) {
        uint32_t a = bm[w], r = rm[w];
        inter += __popc(a & r);
        cnt   += __popc(a);
        rsum  += __popc(r);
    }
#pragma unroll
    for (int off = 32; off; off >>= 1) {
        inter += __shfl_down(inter, off);
        cnt   += __shfl_down(cnt,   off);
        rsum  += __shfl_down(rsum,  off);
    }
    int w = tid >> 6;
    if ((tid & 63) == 0) { red[w] = inter; red[4 + w] = cnt; red[8 + w] = rsum; }
    __syncthreads();
    if (tid == 0) {
        inter = red[0] + red[1] + red[2] + red[3];
        cnt   = red[4] + red[5] + red[6] + red[7];
        rsum  = red[8] + red[9] + red[10] + red[11];
        float uni = (float)(cnt + rsum - inter);
        iou[p] = (uni > 0.0f) ? ((float)inter / fmaxf(uni, 1.0f)) : 0.0f;
    }
}

// ==== Kernel 3: per-scene argmax + small outputs ============================
__global__ void k_select(const float* __restrict__ iou,
                         const float* __restrict__ feats,
                         const int* __restrict__ pes,
                         float* __restrict__ out) {
    __shared__ float s_val[2];
    __shared__ int   s_idx[2];
    __shared__ int   s_best;
    int b = blockIdx.x;
    int t = threadIdx.x;                              // 0 .. 127
    int p = b * PPS + t;
    float v = iou[p];
    int idx = p;
    // wave argmax, first-index tie-break (matches jnp.argmax)
#pragma unroll
    for (int off = 32; off; off >>= 1) {
        float ov = __shfl_down(v,   off);
        int   oi = __shfl_down(idx, off);
        if (ov > v || (ov == v && oi < idx)) { v = ov; idx = oi; }
    }
    if ((t & 63) == 0) { s_val[t >> 6] = v; s_idx[t >> 6] = idx; }
    __syncthreads();
    if (t == 0) {
        float v0 = s_val[0], v1 = s_val[1];
        int   i0 = s_idx[0], i1 = s_idx[1];
        if (v1 > v0 || (v1 == v0 && i1 < i0)) { v0 = v1; i0 = i1; }
        bool has = pes[b] > 0;
        s_best = has ? i0 : -1;
        out[OUT_SELI + b] = has ? (float)i0 : -1.0f;
        out[OUT_MASK + b] = (v0 > 0.2f && has) ? 1.0f : 0.0f;
    }
    __syncthreads();
    int best = s_best;
    if (t < NC)
        out[OUT_SELF + b * NC + t] = (best >= 0) ? feats[best * NC + t] : 0.0f;
    if (b == 0 && t <= NB) {  // offsets = [0, cumsum(proposal_each_scene)]
        int s = 0;
        for (int i = 0; i < t; ++i) s += pes[i];
        out[OUT_OFFS + t] = (float)s;
    }
}

// ===========================================================================

extern "C" void kernel_launch(void* const* d_in, const int* in_sizes, int n_in,
                              void* d_out, int out_size, void* d_ws, size_t ws_size,
                              hipStream_t stream) {
    const int*   proposals_idx = (const int*)d_in[0];
    const int*   pes           = (const int*)d_in[1];
    const int*   labels        = (const int*)d_in[2];
    const int*   object_id     = (const int*)d_in[3];
    const float* feats         = (const float*)d_in[4];

    const int M = in_sizes[0] / 2;
    float* out = (float*)d_out;

    uint32_t* refMask = (uint32_t*)((char*)d_ws + WS_REF_OFF);
    float*    iou     = (float*)   ((char*)d_ws + WS_IOU_OFF);
    uint32_t* gcnt    = (uint32_t*)((char*)d_ws + WS_CNT_OFF);
    uint16_t* sortedN = (uint16_t*)((char*)d_ws + WS_SORT_OFF);

    // zero only the 2 KB bucket counters (ws is poisoned 0xAA each launch)
    hipMemsetAsync(gcnt, 0, PTOT * sizeof(uint32_t), stream);

    k_fused_build<<<NBLK + 1024, 256, 0, stream>>>(
        (const int2*)proposals_idx, M, labels, object_id,
        (const float4*)feats, (float4*)(out + OUT_CLUS),
        gcnt, refMask, sortedN);

    k_iou_fused<<<PTOT, 256, 0, stream>>>(sortedN, gcnt, refMask, iou);

    k_select<<<NB, PPS, 0, stream>>>(iou, feats, pes, out);
}